// Round 5
// baseline (196.072 us; speedup 1.0000x reference)
//
#include <hip/hip_runtime.h>
#include <float.h>
#include <stdint.h>

#define HH 128
#define NROWS 32768
#define KCODES 4096

typedef _Float16 half8 __attribute__((ext_vector_type(8)));
typedef _Float16 half4_t __attribute__((ext_vector_type(4)));
typedef float floatx4 __attribute__((ext_vector_type(4)));
typedef float floatx16 __attribute__((ext_vector_type(16)));

// ---------------------------------------------------------------------------
// Fast path. w pre-split into hi/lo fp16, stored in A-operand fragment order
// (codes = M = reg-indexed rows). Main kernel: w streams through L1 into
// VGPRs (no LDS, no barriers in the k-loop); z lives in registers as the
// B-operand (rows = N = lane-indexed cols), so the argmin state is per-lane:
// best[2]/bidx[2] only. Each wave covers 64 rows x 1024 codes -> per-CU
// VGPR-fill traffic 4 MB (vs 8 MB in R4) < MFMA floor.
//
// wfrag layout (2 MB at d_ws+16384): chunk ci = (code>>5)*8 + s, s = h/16.
// chunk = 2048 B: hi half8[64] then lo half8[64]; entry lane = kh*32 + (code&31)
// holds w[code][h = s*16 + kh*8 .. +8].
// ---------------------------------------------------------------------------

__global__ __launch_bounds__(256) void vq_prep_frag(const float* __restrict__ w,
                                                    float* __restrict__ wsq,
                                                    ushort* __restrict__ wfrag,
                                                    float* __restrict__ loss_slot) {
    const int tid = blockIdx.x * 256 + threadIdx.x;    // 65536 = 4096 codes x 16
    if (tid == 0) loss_slot[0] = 0.0f;                 // d_out poisoned each launch
    const int c  = tid >> 4;                           // code
    const int hg = tid & 15;                           // h/8 group
    const int s  = hg >> 1, kh = hg & 1;

    const float4* src = reinterpret_cast<const float4*>(w + (size_t)c * HH + (hg << 3));
    float4 a = src[0], b = src[1];

    _Float16 h0 = (_Float16)a.x, h1 = (_Float16)a.y, h2 = (_Float16)a.z, h3 = (_Float16)a.w;
    _Float16 h4 = (_Float16)b.x, h5 = (_Float16)b.y, h6 = (_Float16)b.z, h7 = (_Float16)b.w;
    half8 hi = {h0, h1, h2, h3, h4, h5, h6, h7};
    half8 lo = {(_Float16)(a.x - (float)h0), (_Float16)(a.y - (float)h1),
                (_Float16)(a.z - (float)h2), (_Float16)(a.w - (float)h3),
                (_Float16)(b.x - (float)h4), (_Float16)(b.y - (float)h5),
                (_Float16)(b.z - (float)h6), (_Float16)(b.w - (float)h7)};

    const size_t ci = (size_t)(((c >> 5) << 3) | s);
    ushort* dst = wfrag + (ci << 10);                  // 1024 ushorts per chunk
    const int e = ((kh << 5) + (c & 31)) << 3;
    *reinterpret_cast<half8*>(dst + e)       = hi;
    *reinterpret_cast<half8*>(dst + 512 + e) = lo;

    float ssq = 0.0f;
    ssq = fmaf(a.x, a.x, ssq); ssq = fmaf(a.y, a.y, ssq);
    ssq = fmaf(a.z, a.z, ssq); ssq = fmaf(a.w, a.w, ssq);
    ssq = fmaf(b.x, b.x, ssq); ssq = fmaf(b.y, b.y, ssq);
    ssq = fmaf(b.z, b.z, ssq); ssq = fmaf(b.w, b.w, ssq);
    ssq += __shfl_xor(ssq, 1, 64);
    ssq += __shfl_xor(ssq, 2, 64);
    ssq += __shfl_xor(ssq, 4, 64);
    ssq += __shfl_xor(ssq, 8, 64);
    if (hg == 0) wsq[c] = ssq;
}

__global__ __launch_bounds__(256, 2) void vq_main_fast(
        const float* __restrict__ z, const float* __restrict__ w,
        const float* __restrict__ wsq, const ushort* __restrict__ wfrag,
        float* __restrict__ out_zq, float* __restrict__ out_idx,
        float* __restrict__ out_loss) {
    __shared__ float epmin[256];    // [wave][row 0..63]
    __shared__ int   epidx[256];
    __shared__ int   fbidx[64];
    __shared__ float lred[4];

    const int t = threadIdx.x;
    const int lane = t & 63, cq = t >> 6;   // cq: which 1024-code quarter
    const int n = lane & 31, kh = lane >> 5;
    const int rowBase = blockIdx.x * 64;

    // ---- z B-fragments in registers: rows rowBase+n and rowBase+n+32 ----
    // B layout (32x32x16): col = lane&31, k = (lane>>5)*8 + j  (role-symmetric
    // with the A layout verified in R2-R4)
    half8 zbh[2][8], zbl[2][8];
#pragma unroll
    for (int ng = 0; ng < 2; ++ng) {
        const float* zr = z + (size_t)(rowBase + (ng << 5) + n) * HH + (kh << 3);
#pragma unroll
        for (int s = 0; s < 8; ++s) {
            float4 a = *reinterpret_cast<const float4*>(zr + (s << 4));
            float4 b = *reinterpret_cast<const float4*>(zr + (s << 4) + 4);
            _Float16 h0 = (_Float16)a.x, h1 = (_Float16)a.y,
                     h2 = (_Float16)a.z, h3 = (_Float16)a.w;
            _Float16 h4 = (_Float16)b.x, h5 = (_Float16)b.y,
                     h6 = (_Float16)b.z, h7 = (_Float16)b.w;
            zbh[ng][s] = (half8){h0, h1, h2, h3, h4, h5, h6, h7};
            zbl[ng][s] = (half8){(_Float16)(a.x - (float)h0), (_Float16)(a.y - (float)h1),
                                 (_Float16)(a.z - (float)h2), (_Float16)(a.w - (float)h3),
                                 (_Float16)(b.x - (float)h4), (_Float16)(b.y - (float)h5),
                                 (_Float16)(b.z - (float)h6), (_Float16)(b.w - (float)h7)};
        }
    }

    const half8* wf = reinterpret_cast<const half8*>(wfrag) + lane;
    auto ldw = [&](int u, half8& h, half8& l) {
        const half8* p = wf + ((size_t)((cq << 8) + u) << 7);  // 128 half8/chunk
        h = p[0];
        l = p[64];
    };

    // depth-4 rotating prefetch of w A-fragments
    half8 whb[4], wlb[4];
#pragma unroll
    for (int p = 0; p < 4; ++p) ldw(p, whb[p], wlb[p]);

    float best[2] = {FLT_MAX, FLT_MAX};
    int   bidx[2] = {0, 0};

    const float* wqbase = wsq + (cq << 10) + (kh << 2);

#pragma unroll 1
    for (int it = 0; it < 32; ++it) {
        const float* wqp = wqbase + (it << 5);
        floatx4 wq0 = *reinterpret_cast<const floatx4*>(wqp);
        floatx4 wq1 = *reinterpret_cast<const floatx4*>(wqp + 8);
        floatx4 wq2 = *reinterpret_cast<const floatx4*>(wqp + 16);
        floatx4 wq3 = *reinterpret_cast<const floatx4*>(wqp + 24);

        floatx16 acc0, acc1;
#pragma unroll
        for (int r = 0; r < 16; ++r) { acc0[r] = 0.0f; acc1[r] = 0.0f; }

        const int u0 = it << 3;
#pragma unroll
        for (int s = 0; s < 8; ++s) {
            half8 wh = whb[s & 3], wl = wlb[s & 3];
            ldw((u0 + s + 4) & 255, whb[s & 3], wlb[s & 3]);   // wrap tail unused
            // dot = zh*wh + zl*wh + zh*wl (zl*wl ~2^-22, dropped);
            // ng0/ng1 interleave breaks the acc dependency chain
            acc0 = __builtin_amdgcn_mfma_f32_32x32x16_f16(wh, zbh[0][s], acc0, 0, 0, 0);
            acc1 = __builtin_amdgcn_mfma_f32_32x32x16_f16(wh, zbh[1][s], acc1, 0, 0, 0);
            acc0 = __builtin_amdgcn_mfma_f32_32x32x16_f16(wh, zbl[0][s], acc0, 0, 0, 0);
            acc1 = __builtin_amdgcn_mfma_f32_32x32x16_f16(wh, zbl[1][s], acc1, 0, 0, 0);
            acc0 = __builtin_amdgcn_mfma_f32_32x32x16_f16(wl, zbh[0][s], acc0, 0, 0, 0);
            acc1 = __builtin_amdgcn_mfma_f32_32x32x16_f16(wl, zbh[1][s], acc1, 0, 0, 0);
        }

        // C/D: col = lane&31 = z-row, row(code-in-tile) = (r&3)+8*(r>>2)+4*kh
        const int cbase = (cq << 10) + (it << 5) + (kh << 2);
#pragma unroll
        for (int r = 0; r < 16; ++r) {
            const float wqv = (r < 4) ? wq0[r & 3] : (r < 8) ? wq1[r & 3]
                            : (r < 12) ? wq2[r & 3] : wq3[r & 3];
            const int code = cbase + (r & 3) + ((r >> 2) << 3);  // ascending in r
            float s0 = fmaf(-2.0f, acc0[r], wqv);
            if (s0 < best[0]) { best[0] = s0; bidx[0] = code; }  // strict < = first-min
            float s1 = fmaf(-2.0f, acc1[r], wqv);
            if (s1 < best[1]) { best[1] = s1; bidx[1] = code; }
        }
    }

    // ---- merge kh halves (disjoint code sets, same z-row) ----
#pragma unroll
    for (int ng = 0; ng < 2; ++ng) {
        float os = __shfl_xor(best[ng], 32, 64);
        int   oi = __shfl_xor(bidx[ng], 32, 64);
        if (os < best[ng] || (os == best[ng] && oi < bidx[ng])) {
            best[ng] = os; bidx[ng] = oi;
        }
        if (kh == 0) {
            epmin[(cq << 6) + (ng << 5) + n] = best[ng];
            epidx[(cq << 6) + (ng << 5) + n] = bidx[ng];
        }
    }
    __syncthreads();

    // ---- merge the 4 waves' disjoint code quarters (64 rows) ----
    if (t < 64) {
        float bs = epmin[t];
        int   bi = epidx[t];
#pragma unroll
        for (int wv = 1; wv < 4; ++wv) {
            float os = epmin[(wv << 6) + t];
            int   oi = epidx[(wv << 6) + t];
            if (os < bs || (os == bs && oi < bi)) { bs = os; bi = oi; }
        }
        fbidx[t] = bi;
        out_idx[rowBase + t] = (float)bi;
    }
    __syncthreads();

    // ---- gather zq, write out, loss (z re-read from global, exact fp32) ----
    const float4* z4 = reinterpret_cast<const float4*>(z);
    float lsum = 0.0f;
#pragma unroll
    for (int i = 0; i < 8; ++i) {
        int g = i * 256 + t;
        int r = g >> 5, f4 = g & 31;
        int code = fbidx[r];
        float4 wv = *reinterpret_cast<const float4*>(w + (size_t)code * HH + (f4 << 2));
        float4 zv = z4[(size_t)(rowBase + r) * 32 + f4];
        float dx = wv.x - zv.x, dy = wv.y - zv.y, dz = wv.z - zv.z, dw = wv.w - zv.w;
        lsum = fmaf(dx, dx, lsum); lsum = fmaf(dy, dy, lsum);
        lsum = fmaf(dz, dz, lsum); lsum = fmaf(dw, dw, lsum);
        *reinterpret_cast<float4*>(out_zq + (size_t)(rowBase + r) * HH + (f4 << 2)) = wv;
    }
#pragma unroll
    for (int off = 1; off < 64; off <<= 1) lsum += __shfl_xor(lsum, off, 64);
    if (lane == 0) lred[cq] = lsum;
    __syncthreads();
    if (t == 0) {
        float total = lred[0] + lred[1] + lred[2] + lred[3];
        atomicAdd(out_loss, total * (1.25f / 4194304.0f));  // (0.25+1)*mean, N*H
    }
}

// ---------------- fallback path (Round-2 kernel, proven 200 us) -------------
__device__ __forceinline__ int plane_off_fb(int r, int hu) {
    return ((hu << 6) | (r ^ (hu & 7))) << 3;
}

__global__ __launch_bounds__(256) void vq_prep_fb(const float* __restrict__ w,
                                                  float* __restrict__ wsq,
                                                  float* __restrict__ loss_slot) {
    int c = blockIdx.x * 256 + threadIdx.x;
    if (c == 0) loss_slot[0] = 0.0f;
    if (c < KCODES) {
        const float4* row = reinterpret_cast<const float4*>(w + (size_t)c * HH);
        float s = 0.0f;
#pragma unroll
        for (int i = 0; i < HH / 4; ++i) {
            float4 v = row[i];
            s = fmaf(v.x, v.x, s); s = fmaf(v.y, v.y, s);
            s = fmaf(v.z, v.z, s); s = fmaf(v.w, v.w, s);
        }
        wsq[c] = s;
    }
}

__device__ __forceinline__ void stage_tile_fb(const float4* __restrict__ src4,
                                              ushort* lds, int hi_base, int lo_base,
                                              int t) {
#pragma unroll
    for (int p = 0; p < 8; ++p) {
        int g = p * 256 + t;
        int r = g >> 5, f4 = g & 31;
        float4 v = src4[g];
        _Float16 h0 = (_Float16)v.x, h1 = (_Float16)v.y,
                 h2 = (_Float16)v.z, h3 = (_Float16)v.w;
        half4_t hv = {h0, h1, h2, h3};
        half4_t lv = {(_Float16)(v.x - (float)h0), (_Float16)(v.y - (float)h1),
                      (_Float16)(v.z - (float)h2), (_Float16)(v.w - (float)h3)};
        int off = plane_off_fb(r, f4 >> 1) + ((f4 & 1) << 2);
        *reinterpret_cast<half4_t*>(&lds[hi_base + off]) = hv;
        *reinterpret_cast<half4_t*>(&lds[lo_base + off]) = lv;
    }
}

__global__ __launch_bounds__(256, 2) void vq_main_fb(const float* __restrict__ z,
                                                     const float* __restrict__ w,
                                                     const float* __restrict__ wsq,
                                                     float* __restrict__ out_zq,
                                                     float* __restrict__ out_idx,
                                                     float* __restrict__ out_loss) {
    __shared__ __align__(16) ushort lds[32768];
    const int t = threadIdx.x, lane = t & 63, wid = t >> 6;
    const int q = lane >> 4, m15 = lane & 15;
    const int wrow = (wid >> 1) << 5, wcol = (wid & 1) << 5;
    const int rowBase = blockIdx.x * 64;

    stage_tile_fb(reinterpret_cast<const float4*>(z + (size_t)rowBase * HH), lds, 0, 8192, t);

    float best[2][4]; int bidx[2][4];
#pragma unroll
    for (int mt = 0; mt < 2; ++mt)
#pragma unroll
        for (int rg = 0; rg < 4; ++rg) { best[mt][rg] = FLT_MAX; bidx[mt][rg] = 0; }

    const int ar0 = wrow + m15, bn0 = wcol + m15;

    for (int k0 = 0; k0 < KCODES; k0 += 64) {
        __syncthreads();
        stage_tile_fb(reinterpret_cast<const float4*>(w + (size_t)k0 * HH), lds, 16384, 24576, t);
        __syncthreads();
        floatx4 acc[2][2];
#pragma unroll
        for (int mt = 0; mt < 2; ++mt)
#pragma unroll
            for (int nt = 0; nt < 2; ++nt) acc[mt][nt] = (floatx4){0.f, 0.f, 0.f, 0.f};
#pragma unroll
        for (int c = 0; c < 4; ++c) {
            const int hu = (c << 2) + q;
            half8 zh0 = *reinterpret_cast<half8*>(&lds[plane_off_fb(ar0, hu)]);
            half8 zh1 = *reinterpret_cast<half8*>(&lds[plane_off_fb(ar0 + 16, hu)]);
            half8 zl0 = *reinterpret_cast<half8*>(&lds[8192 + plane_off_fb(ar0, hu)]);
            half8 zl1 = *reinterpret_cast<half8*>(&lds[8192 + plane_off_fb(ar0 + 16, hu)]);
            half8 wh0 = *reinterpret_cast<half8*>(&lds[16384 + plane_off_fb(bn0, hu)]);
            half8 wh1 = *reinterpret_cast<half8*>(&lds[16384 + plane_off_fb(bn0 + 16, hu)]);
            half8 wl0 = *reinterpret_cast<half8*>(&lds[24576 + plane_off_fb(bn0, hu)]);
            half8 wl1 = *reinterpret_cast<half8*>(&lds[24576 + plane_off_fb(bn0 + 16, hu)]);
            acc[0][0] = __builtin_amdgcn_mfma_f32_16x16x32_f16(zh0, wh0, acc[0][0], 0, 0, 0);
            acc[0][1] = __builtin_amdgcn_mfma_f32_16x16x32_f16(zh0, wh1, acc[0][1], 0, 0, 0);
            acc[1][0] = __builtin_amdgcn_mfma_f32_16x16x32_f16(zh1, wh0, acc[1][0], 0, 0, 0);
            acc[1][1] = __builtin_amdgcn_mfma_f32_16x16x32_f16(zh1, wh1, acc[1][1], 0, 0, 0);
            acc[0][0] = __builtin_amdgcn_mfma_f32_16x16x32_f16(zh0, wl0, acc[0][0], 0, 0, 0);
            acc[0][1] = __builtin_amdgcn_mfma_f32_16x16x32_f16(zh0, wl1, acc[0][1], 0, 0, 0);
            acc[1][0] = __builtin_amdgcn_mfma_f32_16x16x32_f16(zh1, wl0, acc[1][0], 0, 0, 0);
            acc[1][1] = __builtin_amdgcn_mfma_f32_16x16x32_f16(zh1, wl1, acc[1][1], 0, 0, 0);
            acc[0][0] = __builtin_amdgcn_mfma_f32_16x16x32_f16(zl0, wh0, acc[0][0], 0, 0, 0);
            acc[0][1] = __builtin_amdgcn_mfma_f32_16x16x32_f16(zl0, wh1, acc[0][1], 0, 0, 0);
            acc[1][0] = __builtin_amdgcn_mfma_f32_16x16x32_f16(zl1, wh0, acc[1][0], 0, 0, 0);
            acc[1][1] = __builtin_amdgcn_mfma_f32_16x16x32_f16(zl1, wh1, acc[1][1], 0, 0, 0);
        }
        float wq0 = wsq[k0 + bn0], wq1 = wsq[k0 + bn0 + 16];
#pragma unroll
        for (int mt = 0; mt < 2; ++mt)
#pragma unroll
            for (int nt = 0; nt < 2; ++nt) {
                int code = k0 + wcol + (nt << 4) + m15;
                float wqv = nt ? wq1 : wq0;
#pragma unroll
                for (int rg = 0; rg < 4; ++rg) {
                    float s = fmaf(-2.0f, acc[mt][nt][rg], wqv);
                    if (s < best[mt][rg]) { best[mt][rg] = s; bidx[mt][rg] = code; }
                }
            }
    }
#pragma unroll
    for (int off = 1; off < 16; off <<= 1)
#pragma unroll
        for (int mt = 0; mt < 2; ++mt)
#pragma unroll
            for (int rg = 0; rg < 4; ++rg) {
                float os = __shfl_xor(best[mt][rg], off, 64);
                int   oi = __shfl_xor(bidx[mt][rg], off, 64);
                if (os < best[mt][rg] || (os == best[mt][rg] && oi < bidx[mt][rg])) {
                    best[mt][rg] = os; bidx[mt][rg] = oi;
                }
            }
    float* epmin = reinterpret_cast<float*>(lds);
    int*   epidx = reinterpret_cast<int*>(reinterpret_cast<char*>(lds) + 512);
    int*   fbidx = reinterpret_cast<int*>(reinterpret_cast<char*>(lds) + 1024);
    float* lred  = reinterpret_cast<float*>(reinterpret_cast<char*>(lds) + 1280);
    __syncthreads();
    if (m15 == 0) {
        int g = wid & 1;
#pragma unroll
        for (int mt = 0; mt < 2; ++mt)
#pragma unroll
            for (int rg = 0; rg < 4; ++rg) {
                int row = wrow + (mt << 4) + (q << 2) + rg;
                epmin[g * 64 + row] = best[mt][rg];
                epidx[g * 64 + row] = bidx[mt][rg];
            }
    }
    __syncthreads();
    if (t < 64) {
        float s0 = epmin[t], s1 = epmin[64 + t];
        int   i0 = epidx[t], i1 = epidx[64 + t];
        int   fi = (s1 < s0 || (s1 == s0 && i1 < i0)) ? i1 : i0;
        fbidx[t] = fi;
        out_idx[rowBase + t] = (float)fi;
    }
    __syncthreads();
    const float4* z4 = reinterpret_cast<const float4*>(z);
    float lsum = 0.0f;
#pragma unroll
    for (int i = 0; i < 8; ++i) {
        int g = i * 256 + t;
        int r = g >> 5, f4 = g & 31;
        int code = fbidx[r];
        float4 wv = *reinterpret_cast<const float4*>(w + (size_t)code * HH + (f4 << 2));
        float4 zv = z4[(size_t)(rowBase + r) * 32 + f4];
        float dx = wv.x - zv.x, dy = wv.y - zv.y, dz = wv.z - zv.z, dw = wv.w - zv.w;
        lsum = fmaf(dx, dx, lsum); lsum = fmaf(dy, dy, lsum);
        lsum = fmaf(dz, dz, lsum); lsum = fmaf(dw, dw, lsum);
        *reinterpret_cast<float4*>(out_zq + (size_t)(rowBase + r) * HH + (f4 << 2)) = wv;
    }
#pragma unroll
    for (int off = 1; off < 64; off <<= 1) lsum += __shfl_xor(lsum, off, 64);
    if (lane == 0) lred[wid] = lsum;
    __syncthreads();
    if (t == 0)
        atomicAdd(out_loss, (lred[0] + lred[1] + lred[2] + lred[3]) * (1.25f / 4194304.0f));
}

extern "C" void kernel_launch(void* const* d_in, const int* in_sizes, int n_in,
                              void* d_out, int out_size, void* d_ws, size_t ws_size,
                              hipStream_t stream) {
    (void)in_sizes; (void)n_in; (void)out_size;
    const float* z = (const float*)d_in[0];
    const float* w = (const float*)d_in[1];
    float* out      = (float*)d_out;
    float* out_zq   = out;
    float* out_idx  = out + (size_t)NROWS * HH;
    float* out_loss = out_idx + NROWS;
    float* wsq = (float*)d_ws;

    const size_t WS_NEED = 16384 + (size_t)KCODES * HH * 2 * 2;  // wsq + frag planes
    if (ws_size >= WS_NEED) {
        ushort* wfrag = (ushort*)((char*)d_ws + 16384);
        vq_prep_frag<<<(KCODES * 16) / 256, 256, 0, stream>>>(w, wsq, wfrag, out_loss);
        vq_main_fast<<<NROWS / 64, 256, 0, stream>>>(z, w, wsq, wfrag,
                                                     out_zq, out_idx, out_loss);
    } else {
        vq_prep_fb<<<KCODES / 256, 256, 0, stream>>>(w, wsq, out_loss);
        vq_main_fb<<<NROWS / 64, 256, 0, stream>>>(z, w, wsq, out_zq, out_idx, out_loss);
    }
}

// Round 6
// 188.887 us; speedup vs baseline: 1.0380x; 1.0380x over previous
//
#include <hip/hip_runtime.h>
#include <float.h>
#include <stdint.h>

#define HH 128
#define NROWS 32768
#define KCODES 4096
#define CAP 16384   // rescan capacity (rows); est. flagged ~4k, 4x margin

typedef _Float16 half8 __attribute__((ext_vector_type(8)));
typedef _Float16 half4_t __attribute__((ext_vector_type(4)));
typedef float floatx4 __attribute__((ext_vector_type(4)));
typedef float floatx16 __attribute__((ext_vector_type(16)));
typedef const __attribute__((address_space(1))) uint32_t gbl_u32;
typedef __attribute__((address_space(3))) uint32_t lds_u32;

// ---------------------------------------------------------------------------
// ws layout (bytes):                         d_out zq-region scratch (floats):
//   0        wsqR   float[4096]                0       pm1 [2][32768]
//   16384    wlPart float[256]                 65536   pi1 [2][32768] (int)
//   17408    whPart float[256]                 131072  pm2 [2][32768]
//   18432    nFlag  uint (+pad)                196608  znA [32768]
//   18688    whiA   ushort[524288] (1 MB)      229376  zlA [32768]
//   1067264  idxInt int[32768]
//   1198336  slotOf int[32768]
//   1329408  clist  int[16384]
//   1394944  pminR  float[4*16384]
//   1657088  pidxR  int[4*16384]     (end 1919232 <= proven ws >= 2.02 MB)
//
// whiA: A-frag order. 32-code block cb = code>>5; chunk (cb, s=h/16) = 512
// ushorts; entry lane = kh*32 + (code&31) holds w_hi[code][s*16+kh*8 .. +8].
// wsqR[cb*32 + kh*16 + r] = ||w||^2 of code cb*32 + (r&3)+8*(r>>2)+4*kh.
// ---------------------------------------------------------------------------

__device__ __forceinline__ void top2_comb(float& m1, int& i1, float& m2,
                                          float om1, int oi1, float om2) {
    if (om1 < m1 || (om1 == m1 && oi1 < i1)) {
        m2 = fminf(m1, om2); m1 = om1; i1 = oi1;
    } else {
        m2 = fminf(m2, om1);
    }
}

// ------------------------- prep -------------------------------------------
__global__ __launch_bounds__(256) void vq_prep(const float* __restrict__ w,
        float* __restrict__ wsqR, ushort* __restrict__ whiA,
        float* __restrict__ wlPart, float* __restrict__ whPart) {
    __shared__ float sWL[16], sWH[16];
    const int t = threadIdx.x;
    const int tid = blockIdx.x * 256 + t;
    const int c = tid >> 4, hg = tid & 15, s = hg >> 1, kh = hg & 1;

    const float4* src = reinterpret_cast<const float4*>(w + (size_t)c * HH + (hg << 3));
    float4 a = src[0], b = src[1];
    _Float16 h0 = (_Float16)a.x, h1 = (_Float16)a.y, h2 = (_Float16)a.z, h3 = (_Float16)a.w;
    _Float16 h4 = (_Float16)b.x, h5 = (_Float16)b.y, h6 = (_Float16)b.z, h7 = (_Float16)b.w;
    half8 hi = {h0, h1, h2, h3, h4, h5, h6, h7};
    float l0 = a.x - (float)h0, l1 = a.y - (float)h1, l2 = a.z - (float)h2, l3 = a.w - (float)h3;
    float l4 = b.x - (float)h4, l5 = b.y - (float)h5, l6 = b.z - (float)h6, l7 = b.w - (float)h7;

    const int cb = c >> 5;
    const int lane_e = (kh << 5) | (c & 31);
    *reinterpret_cast<half8*>(&whiA[((size_t)cb * 8 + s) * 512 + (lane_e << 3)]) = hi;

    float ssq = 0.f, ssql = 0.f;
    ssq = fmaf(a.x, a.x, ssq); ssq = fmaf(a.y, a.y, ssq);
    ssq = fmaf(a.z, a.z, ssq); ssq = fmaf(a.w, a.w, ssq);
    ssq = fmaf(b.x, b.x, ssq); ssq = fmaf(b.y, b.y, ssq);
    ssq = fmaf(b.z, b.z, ssq); ssq = fmaf(b.w, b.w, ssq);
    ssql = fmaf(l0, l0, ssql); ssql = fmaf(l1, l1, ssql);
    ssql = fmaf(l2, l2, ssql); ssql = fmaf(l3, l3, ssql);
    ssql = fmaf(l4, l4, ssql); ssql = fmaf(l5, l5, ssql);
    ssql = fmaf(l6, l6, ssql); ssql = fmaf(l7, l7, ssql);
#pragma unroll
    for (int off = 1; off < 16; off <<= 1) {
        ssq  += __shfl_xor(ssq,  off, 64);
        ssql += __shfl_xor(ssql, off, 64);
    }
    if (hg == 0) {
        int ridx = (c & 3) + (((c >> 3) & 3) << 2);
        wsqR[cb * 32 + (((c >> 2) & 1) << 4) + ridx] = ssq;
        sWL[t >> 4] = ssql;
        sWH[t >> 4] = ssq;
    }
    __syncthreads();
    if (t == 0) {
        float ml = 0.f, mh = 0.f;
#pragma unroll
        for (int i = 0; i < 16; ++i) { ml = fmaxf(ml, sWL[i]); mh = fmaxf(mh, sWH[i]); }
        wlPart[blockIdx.x] = ml;
        whPart[blockIdx.x] = mh;
    }
}

// ------------------------- phase 1: hi-only 1-pass + top2 ------------------
__global__ __launch_bounds__(512, 4) void vq_p1(const float* __restrict__ z,
        const ushort* __restrict__ whiA, const float* __restrict__ wsqR,
        float* __restrict__ pm1, int* __restrict__ pi1, float* __restrict__ pm2,
        float* __restrict__ znA, float* __restrict__ zlA,
        unsigned int* __restrict__ nFlag) {
    __shared__ __align__(16) ushort buf[32768];   // 2 x 32 KB dbuf

    const int t = threadIdx.x;
    const int lane = t & 63, wid = t >> 6;
    const int q = wid & 3, g = wid >> 2;          // code-quarter, row-group
    const int n = lane & 31, kh = lane >> 5;
    const int rg = blockIdx.x >> 1, hf = blockIdx.x & 1;
    const int rowBase = rg * 64;
    const int myRow = rowBase + g * 32 + n;

    if (t == 0) *nFlag = 0u;   // all p1 blocks write 0; read later by vq_flag

    // ---- z hi B-fragments + exact row norms (||z||^2, ||z_lo||^2) ----
    half8 zb[8];
    float zn2 = 0.f, zl2 = 0.f;
    {
        const float* zr = z + (size_t)myRow * HH + (kh << 3);
#pragma unroll
        for (int s = 0; s < 8; ++s) {
            float4 a = *reinterpret_cast<const float4*>(zr + (s << 4));
            float4 b = *reinterpret_cast<const float4*>(zr + (s << 4) + 4);
            _Float16 h0 = (_Float16)a.x, h1 = (_Float16)a.y,
                     h2 = (_Float16)a.z, h3 = (_Float16)a.w;
            _Float16 h4 = (_Float16)b.x, h5 = (_Float16)b.y,
                     h6 = (_Float16)b.z, h7 = (_Float16)b.w;
            zb[s] = (half8){h0, h1, h2, h3, h4, h5, h6, h7};
            zn2 = fmaf(a.x, a.x, zn2); zn2 = fmaf(a.y, a.y, zn2);
            zn2 = fmaf(a.z, a.z, zn2); zn2 = fmaf(a.w, a.w, zn2);
            zn2 = fmaf(b.x, b.x, zn2); zn2 = fmaf(b.y, b.y, zn2);
            zn2 = fmaf(b.z, b.z, zn2); zn2 = fmaf(b.w, b.w, zn2);
            float l0 = a.x - (float)h0, l1 = a.y - (float)h1,
                  l2 = a.z - (float)h2, l3 = a.w - (float)h3;
            float l4 = b.x - (float)h4, l5 = b.y - (float)h5,
                  l6 = b.z - (float)h6, l7 = b.w - (float)h7;
            zl2 = fmaf(l0, l0, zl2); zl2 = fmaf(l1, l1, zl2);
            zl2 = fmaf(l2, l2, zl2); zl2 = fmaf(l3, l3, zl2);
            zl2 = fmaf(l4, l4, zl2); zl2 = fmaf(l5, l5, zl2);
            zl2 = fmaf(l6, l6, zl2); zl2 = fmaf(l7, l7, zl2);
        }
        zn2 += __shfl_xor(zn2, 32, 64);
        zl2 += __shfl_xor(zl2, 32, 64);
        if (hf == 0 && q == 0 && kh == 0) { znA[myRow] = zn2; zlA[myRow] = zl2; }
    }

    // ---- DMA: wave (q,g) stages s' = g*4..g*4+3 of its quarter ----
    auto pref = [&](int tile, int b) {
        const int cbg = ((hf * 16 + tile) << 2) + q;
        const ushort* src = whiA + ((size_t)cbg * 8 + (g << 2)) * 512 + (lane << 3);
        ushort* dst = buf + (b << 14) + (q << 12) + ((g << 2) << 9);
#pragma unroll
        for (int p = 0; p < 4; ++p) {
            __builtin_amdgcn_global_load_lds((gbl_u32*)(src + p * 512),
                                             (lds_u32*)(dst + p * 512), 16, 0, 0);
        }
    };

    float m1 = FLT_MAX, m2 = FLT_MAX;
    int i1 = 0;

    pref(0, 0);
    __syncthreads();

#pragma unroll 1
    for (int tile = 0; tile < 16; ++tile) {
        const int b = tile & 1;
        if (tile < 15) pref(tile + 1, b ^ 1);
        const int cbg = ((hf * 16 + tile) << 2) + q;
        const float* wqp = wsqR + cbg * 32 + (kh << 4);
        floatx4 w0 = *reinterpret_cast<const floatx4*>(wqp);
        floatx4 w1 = *reinterpret_cast<const floatx4*>(wqp + 4);
        floatx4 w2 = *reinterpret_cast<const floatx4*>(wqp + 8);
        floatx4 w3 = *reinterpret_cast<const floatx4*>(wqp + 12);

        const ushort* wb = buf + (b << 14) + (q << 12);
        floatx16 accA, accB;
#pragma unroll
        for (int r = 0; r < 16; ++r) { accA[r] = 0.f; accB[r] = 0.f; }
#pragma unroll
        for (int s = 0; s < 4; ++s) {
            half8 af = *reinterpret_cast<const half8*>(&wb[(s << 9) + (lane << 3)]);
            half8 ag = *reinterpret_cast<const half8*>(&wb[((s + 4) << 9) + (lane << 3)]);
            accA = __builtin_amdgcn_mfma_f32_32x32x16_f16(af, zb[s], accA, 0, 0, 0);
            accB = __builtin_amdgcn_mfma_f32_32x32x16_f16(ag, zb[s + 4], accB, 0, 0, 0);
        }
        const int codeBase = cbg * 32 + (kh << 2);
#pragma unroll
        for (int r = 0; r < 16; ++r) {
            float wqv = (r < 4) ? w0[r & 3] : (r < 8) ? w1[r & 3]
                      : (r < 12) ? w2[r & 3] : w3[r & 3];
            float sc = fmaf(-2.0f, accA[r] + accB[r], wqv);
            int code = codeBase + (r & 3) + ((r >> 2) << 3);
            // scan order strictly ascending in code -> strict < keeps first-min
            bool lt = sc < m1;
            m2 = lt ? m1 : fminf(m2, sc);
            i1 = lt ? code : i1;
            m1 = lt ? sc : m1;
        }
        __syncthreads();
    }

    // merge kh halves (same row, disjoint codes)
    {
        float om1 = __shfl_xor(m1, 32, 64), om2 = __shfl_xor(m2, 32, 64);
        int oi1 = __shfl_xor(i1, 32, 64);
        top2_comb(m1, i1, m2, om1, oi1, om2);
    }
    // merge quarters via LDS (aliased over dead buf)
    float* sm1 = reinterpret_cast<float*>(buf);
    int*   si1 = reinterpret_cast<int*>(buf + 512);
    float* sm2 = reinterpret_cast<float*>(buf + 1024);
    if (kh == 0) {
        sm1[q * 64 + g * 32 + n] = m1;
        si1[q * 64 + g * 32 + n] = i1;
        sm2[q * 64 + g * 32 + n] = m2;
    }
    __syncthreads();
    if (t < 64) {
        float fm1 = sm1[t], fm2 = sm2[t];
        int fi1 = si1[t];
#pragma unroll
        for (int qq = 1; qq < 4; ++qq)
            top2_comb(fm1, fi1, fm2, sm1[qq * 64 + t], si1[qq * 64 + t], sm2[qq * 64 + t]);
        pm1[hf * NROWS + rowBase + t] = fm1;
        pi1[hf * NROWS + rowBase + t] = fi1;
        pm2[hf * NROWS + rowBase + t] = fm2;
    }
}

// ------------------------- flag + compact ----------------------------------
__global__ __launch_bounds__(256) void vq_flag(const float* __restrict__ pm1,
        const int* __restrict__ pi1, const float* __restrict__ pm2,
        const float* __restrict__ znA, const float* __restrict__ zlA,
        const float* __restrict__ wlPart, const float* __restrict__ whPart,
        int* __restrict__ idxInt, int* __restrict__ slotOf, int* __restrict__ clist,
        unsigned int* __restrict__ nFlag, float* __restrict__ loss_slot) {
    __shared__ float sred[8];
    const int t = threadIdx.x, lane = t & 63, wid = t >> 6;
    if (blockIdx.x == 0 && t == 0) *loss_slot = 0.0f;

    // reduce codebook maxima (256 partials)
    float wl2 = wlPart[t], wh2 = whPart[t];
#pragma unroll
    for (int off = 1; off < 64; off <<= 1) {
        wl2 = fmaxf(wl2, __shfl_xor(wl2, off, 64));
        wh2 = fmaxf(wh2, __shfl_xor(wh2, off, 64));
    }
    if (lane == 0) { sred[wid] = wl2; sred[4 + wid] = wh2; }
    __syncthreads();
    float WL = sqrtf(fmaxf(fmaxf(sred[0], sred[1]), fmaxf(sred[2], sred[3])));
    float WH = sqrtf(fmaxf(fmaxf(sred[4], sred[5]), fmaxf(sred[6], sred[7])));

    const int row = blockIdx.x * 256 + t;
    float m1 = pm1[row], m2 = pm2[row];
    int i1 = pi1[row];
    top2_comb(m1, i1, m2, pm1[NROWS + row], pi1[NROWS + row], pm2[NROWS + row]);
    idxInt[row] = i1;

    // rigorous safety margin: |d_true - d_hat| <= 2(||z||*WL + ||z_lo||*WH);
    // flag if m2-m1 <= 2E*1.1 + slack
    float zn = sqrtf(znA[row]), zln = sqrtf(zlA[row]);
    float thr = 4.4f * (zn * WL + zln * WH) + 0.1f;
    bool flag = (m2 - m1) <= thr;

    unsigned long long mask = __ballot(flag);
    unsigned int base = 0;
    if (lane == 0) base = atomicAdd(nFlag, (unsigned int)__popcll(mask));
    base = __shfl((int)base, 0, 64);
    unsigned int pos = base + __popcll(mask & ((1ull << lane) - 1ull));
    int so = -1;
    if (flag && pos < CAP) { clist[pos] = row; so = (int)pos; }
    slotOf[row] = so;
}

// ------------------------- rescan: exact 3-pass on flagged rows -------------
__global__ __launch_bounds__(256) void vq_rescan(const float* __restrict__ z,
        const float* __restrict__ w, const ushort* __restrict__ whiA,
        const float* __restrict__ wsqR, const int* __restrict__ clist,
        const unsigned int* __restrict__ nFlag,
        float* __restrict__ pminR, int* __restrict__ pidxR) {
    const int p = blockIdx.x & 3, slot = blockIdx.x >> 2;
    int cnt = (int)*nFlag; if (cnt > CAP) cnt = CAP;
    if (slot * 64 >= cnt) return;

    __shared__ float smn[4][64];
    __shared__ int   sid[4][64];

    const int t = threadIdx.x, lane = t & 63, wv = t >> 6;
    const int n = lane & 31, kh = lane >> 5;

    // rows (2 groups of 32), pad with first entry of the slot
    int e0 = slot * 64 + n, e1 = slot * 64 + 32 + n;
    int r0 = clist[e0 < cnt ? e0 : slot * 64];
    int r1 = clist[e1 < cnt ? e1 : slot * 64];

    half8 zh[2][8], zl[2][8];
#pragma unroll
    for (int ng = 0; ng < 2; ++ng) {
        const float* zr = z + (size_t)(ng ? r1 : r0) * HH + (kh << 3);
#pragma unroll
        for (int s = 0; s < 8; ++s) {
            float4 a = *reinterpret_cast<const float4*>(zr + (s << 4));
            float4 b = *reinterpret_cast<const float4*>(zr + (s << 4) + 4);
            _Float16 h0 = (_Float16)a.x, h1 = (_Float16)a.y,
                     h2 = (_Float16)a.z, h3 = (_Float16)a.w;
            _Float16 h4 = (_Float16)b.x, h5 = (_Float16)b.y,
                     h6 = (_Float16)b.z, h7 = (_Float16)b.w;
            zh[ng][s] = (half8){h0, h1, h2, h3, h4, h5, h6, h7};
            zl[ng][s] = (half8){(_Float16)(a.x - (float)h0), (_Float16)(a.y - (float)h1),
                                (_Float16)(a.z - (float)h2), (_Float16)(a.w - (float)h3),
                                (_Float16)(b.x - (float)h4), (_Float16)(b.y - (float)h5),
                                (_Float16)(b.z - (float)h6), (_Float16)(b.w - (float)h7)};
        }
    }

    float b0 = FLT_MAX, b1 = FLT_MAX;
    int x0 = 0, x1 = 0;

#pragma unroll 1
    for (int i = 0; i < 8; ++i) {
        const int cb = (p << 5) + (wv << 3) + i;      // ascending scan order
        const int codeRow = (cb << 5) + n;
        floatx16 a0, a1;
#pragma unroll
        for (int r = 0; r < 16; ++r) { a0[r] = 0.f; a1[r] = 0.f; }
#pragma unroll
        for (int s = 0; s < 8; ++s) {
            half8 ah = *reinterpret_cast<const half8*>(
                &whiA[((size_t)cb * 8 + s) * 512 + (lane << 3)]);
            const float* wr = w + (size_t)codeRow * HH + (s << 4) + (kh << 3);
            float4 fa = *reinterpret_cast<const float4*>(wr);
            float4 fb = *reinterpret_cast<const float4*>(wr + 4);
            half8 al = {(_Float16)(fa.x - (float)ah[0]), (_Float16)(fa.y - (float)ah[1]),
                        (_Float16)(fa.z - (float)ah[2]), (_Float16)(fa.w - (float)ah[3]),
                        (_Float16)(fb.x - (float)ah[4]), (_Float16)(fb.y - (float)ah[5]),
                        (_Float16)(fb.z - (float)ah[6]), (_Float16)(fb.w - (float)ah[7])};
            a0 = __builtin_amdgcn_mfma_f32_32x32x16_f16(ah, zh[0][s], a0, 0, 0, 0);
            a1 = __builtin_amdgcn_mfma_f32_32x32x16_f16(ah, zh[1][s], a1, 0, 0, 0);
            a0 = __builtin_amdgcn_mfma_f32_32x32x16_f16(ah, zl[0][s], a0, 0, 0, 0);
            a1 = __builtin_amdgcn_mfma_f32_32x32x16_f16(ah, zl[1][s], a1, 0, 0, 0);
            a0 = __builtin_amdgcn_mfma_f32_32x32x16_f16(al, zh[0][s], a0, 0, 0, 0);
            a1 = __builtin_amdgcn_mfma_f32_32x32x16_f16(al, zh[1][s], a1, 0, 0, 0);
        }
        const float* wqp = wsqR + cb * 32 + (kh << 4);
        const int codeBase = (cb << 5) + (kh << 2);
#pragma unroll
        for (int r = 0; r < 16; ++r) {
            float wqv = wqp[r];
            int code = codeBase + (r & 3) + ((r >> 2) << 3);
            float s0 = fmaf(-2.0f, a0[r], wqv);
            if (s0 < b0) { b0 = s0; x0 = code; }
            float s1 = fmaf(-2.0f, a1[r], wqv);
            if (s1 < b1) { b1 = s1; x1 = code; }
        }
    }
    // kh merge
    {
        float o = __shfl_xor(b0, 32, 64); int oi = __shfl_xor(x0, 32, 64);
        if (o < b0 || (o == b0 && oi < x0)) { b0 = o; x0 = oi; }
        o = __shfl_xor(b1, 32, 64); oi = __shfl_xor(x1, 32, 64);
        if (o < b1 || (o == b1 && oi < x1)) { b1 = o; x1 = oi; }
    }
    if (kh == 0) {
        smn[wv][n] = b0;      sid[wv][n] = x0;
        smn[wv][32 + n] = b1; sid[wv][32 + n] = x1;
    }
    __syncthreads();
    if (t < 64 && slot * 64 + t < cnt) {
        float m = smn[0][t]; int ix = sid[0][t];
#pragma unroll
        for (int ww = 1; ww < 4; ++ww) {
            float o = smn[ww][t]; int oi = sid[ww][t];
            if (o < m || (o == m && oi < ix)) { m = o; ix = oi; }
        }
        pminR[p * CAP + slot * 64 + t] = m;
        pidxR[p * CAP + slot * 64 + t] = ix;
    }
}

// ------------------------- finalize: idx, zq, loss --------------------------
__global__ __launch_bounds__(256) void vq_final(const float* __restrict__ z,
        const float* __restrict__ w, const int* __restrict__ idxInt,
        const int* __restrict__ slotOf, const float* __restrict__ pminR,
        const int* __restrict__ pidxR, float* __restrict__ out_zq,
        float* __restrict__ out_idx, float* __restrict__ out_loss) {
    __shared__ int fb[64];
    __shared__ float lred[4];
    const int t = threadIdx.x, lane = t & 63, wid = t >> 6;
    const int rowBase = blockIdx.x * 64;

    if (t < 64) {
        int row = rowBase + t;
        int idx = idxInt[row];
        int s = slotOf[row];
        if (s >= 0) {
            float m = pminR[s]; idx = pidxR[s];
#pragma unroll
            for (int p = 1; p < 4; ++p) {
                float o = pminR[p * CAP + s]; int oi = pidxR[p * CAP + s];
                if (o < m || (o == m && oi < idx)) { m = o; idx = oi; }
            }
        }
        fb[t] = idx;
        out_idx[row] = (float)idx;
    }
    __syncthreads();

    const float4* z4 = reinterpret_cast<const float4*>(z);
    float lsum = 0.0f;
#pragma unroll
    for (int i = 0; i < 8; ++i) {
        int g = i * 256 + t;
        int r = g >> 5, f4 = g & 31;
        int code = fb[r];
        float4 wv = *reinterpret_cast<const float4*>(w + (size_t)code * HH + (f4 << 2));
        float4 zv = z4[(size_t)(rowBase + r) * 32 + f4];
        float dx = wv.x - zv.x, dy = wv.y - zv.y, dz = wv.z - zv.z, dw = wv.w - zv.w;
        lsum = fmaf(dx, dx, lsum); lsum = fmaf(dy, dy, lsum);
        lsum = fmaf(dz, dz, lsum); lsum = fmaf(dw, dw, lsum);
        *reinterpret_cast<float4*>(out_zq + (size_t)(rowBase + r) * HH + (f4 << 2)) = wv;
    }
#pragma unroll
    for (int off = 1; off < 64; off <<= 1) lsum += __shfl_xor(lsum, off, 64);
    if (lane == 0) lred[wid] = lsum;
    __syncthreads();
    if (t == 0) {
        float total = lred[0] + lred[1] + lred[2] + lred[3];
        atomicAdd(out_loss, total * (1.25f / 4194304.0f));  // (0.25+1)*mean, N*H
    }
}

// ---------------- fallback path (Round-2 kernels, proven 200 us) ------------
__device__ __forceinline__ int plane_off_fb(int r, int hu) {
    return ((hu << 6) | (r ^ (hu & 7))) << 3;
}

__global__ __launch_bounds__(256) void vq_prep_fb(const float* __restrict__ w,
                                                  float* __restrict__ wsq,
                                                  float* __restrict__ loss_slot) {
    int c = blockIdx.x * 256 + threadIdx.x;
    if (c == 0) loss_slot[0] = 0.0f;
    if (c < KCODES) {
        const float4* row = reinterpret_cast<const float4*>(w + (size_t)c * HH);
        float s = 0.0f;
#pragma unroll
        for (int i = 0; i < HH / 4; ++i) {
            float4 v = row[i];
            s = fmaf(v.x, v.x, s); s = fmaf(v.y, v.y, s);
            s = fmaf(v.z, v.z, s); s = fmaf(v.w, v.w, s);
        }
        wsq[c] = s;
    }
}

__device__ __forceinline__ void stage_tile_fb(const float4* __restrict__ src4,
                                              ushort* lds, int hi_base, int lo_base,
                                              int t) {
#pragma unroll
    for (int p = 0; p < 8; ++p) {
        int g = p * 256 + t;
        int r = g >> 5, f4 = g & 31;
        float4 v = src4[g];
        _Float16 h0 = (_Float16)v.x, h1 = (_Float16)v.y,
                 h2 = (_Float16)v.z, h3 = (_Float16)v.w;
        half4_t hv = {h0, h1, h2, h3};
        half4_t lv = {(_Float16)(v.x - (float)h0), (_Float16)(v.y - (float)h1),
                      (_Float16)(v.z - (float)h2), (_Float16)(v.w - (float)h3)};
        int off = plane_off_fb(r, f4 >> 1) + ((f4 & 1) << 2);
        *reinterpret_cast<half4_t*>(&lds[hi_base + off]) = hv;
        *reinterpret_cast<half4_t*>(&lds[lo_base + off]) = lv;
    }
}

__global__ __launch_bounds__(256, 2) void vq_main_fb(const float* __restrict__ z,
                                                     const float* __restrict__ w,
                                                     const float* __restrict__ wsq,
                                                     float* __restrict__ out_zq,
                                                     float* __restrict__ out_idx,
                                                     float* __restrict__ out_loss) {
    __shared__ __align__(16) ushort lds[32768];
    const int t = threadIdx.x, lane = t & 63, wid = t >> 6;
    const int q = lane >> 4, m15 = lane & 15;
    const int wrow = (wid >> 1) << 5, wcol = (wid & 1) << 5;
    const int rowBase = blockIdx.x * 64;

    stage_tile_fb(reinterpret_cast<const float4*>(z + (size_t)rowBase * HH), lds, 0, 8192, t);

    float best[2][4]; int bidx[2][4];
#pragma unroll
    for (int mt = 0; mt < 2; ++mt)
#pragma unroll
        for (int rg = 0; rg < 4; ++rg) { best[mt][rg] = FLT_MAX; bidx[mt][rg] = 0; }

    const int ar0 = wrow + m15, bn0 = wcol + m15;

    for (int k0 = 0; k0 < KCODES; k0 += 64) {
        __syncthreads();
        stage_tile_fb(reinterpret_cast<const float4*>(w + (size_t)k0 * HH), lds, 16384, 24576, t);
        __syncthreads();
        floatx4 acc[2][2];
#pragma unroll
        for (int mt = 0; mt < 2; ++mt)
#pragma unroll
            for (int nt = 0; nt < 2; ++nt) acc[mt][nt] = (floatx4){0.f, 0.f, 0.f, 0.f};
#pragma unroll
        for (int c = 0; c < 4; ++c) {
            const int hu = (c << 2) + q;
            half8 zh0 = *reinterpret_cast<half8*>(&lds[plane_off_fb(ar0, hu)]);
            half8 zh1 = *reinterpret_cast<half8*>(&lds[plane_off_fb(ar0 + 16, hu)]);
            half8 zl0 = *reinterpret_cast<half8*>(&lds[8192 + plane_off_fb(ar0, hu)]);
            half8 zl1 = *reinterpret_cast<half8*>(&lds[8192 + plane_off_fb(ar0 + 16, hu)]);
            half8 wh0 = *reinterpret_cast<half8*>(&lds[16384 + plane_off_fb(bn0, hu)]);
            half8 wh1 = *reinterpret_cast<half8*>(&lds[16384 + plane_off_fb(bn0 + 16, hu)]);
            half8 wl0 = *reinterpret_cast<half8*>(&lds[24576 + plane_off_fb(bn0, hu)]);
            half8 wl1 = *reinterpret_cast<half8*>(&lds[24576 + plane_off_fb(bn0 + 16, hu)]);
            acc[0][0] = __builtin_amdgcn_mfma_f32_16x16x32_f16(zh0, wh0, acc[0][0], 0, 0, 0);
            acc[0][1] = __builtin_amdgcn_mfma_f32_16x16x32_f16(zh0, wh1, acc[0][1], 0, 0, 0);
            acc[1][0] = __builtin_amdgcn_mfma_f32_16x16x32_f16(zh1, wh0, acc[1][0], 0, 0, 0);
            acc[1][1] = __builtin_amdgcn_mfma_f32_16x16x32_f16(zh1, wh1, acc[1][1], 0, 0, 0);
            acc[0][0] = __builtin_amdgcn_mfma_f32_16x16x32_f16(zh0, wl0, acc[0][0], 0, 0, 0);
            acc[0][1] = __builtin_amdgcn_mfma_f32_16x16x32_f16(zh0, wl1, acc[0][1], 0, 0, 0);
            acc[1][0] = __builtin_amdgcn_mfma_f32_16x16x32_f16(zh1, wl0, acc[1][0], 0, 0, 0);
            acc[1][1] = __builtin_amdgcn_mfma_f32_16x16x32_f16(zh1, wl1, acc[1][1], 0, 0, 0);
            acc[0][0] = __builtin_amdgcn_mfma_f32_16x16x32_f16(zl0, wh0, acc[0][0], 0, 0, 0);
            acc[0][1] = __builtin_amdgcn_mfma_f32_16x16x32_f16(zl0, wh1, acc[0][1], 0, 0, 0);
            acc[1][0] = __builtin_amdgcn_mfma_f32_16x16x32_f16(zl1, wh0, acc[1][0], 0, 0, 0);
            acc[1][1] = __builtin_amdgcn_mfma_f32_16x16x32_f16(zl1, wh1, acc[1][1], 0, 0, 0);
        }
        float wq0 = wsq[k0 + bn0], wq1 = wsq[k0 + bn0 + 16];
#pragma unroll
        for (int mt = 0; mt < 2; ++mt)
#pragma unroll
            for (int nt = 0; nt < 2; ++nt) {
                int code = k0 + wcol + (nt << 4) + m15;
                float wqv = nt ? wq1 : wq0;
#pragma unroll
                for (int rg = 0; rg < 4; ++rg) {
                    float s = fmaf(-2.0f, acc[mt][nt][rg], wqv);
                    if (s < best[mt][rg]) { best[mt][rg] = s; bidx[mt][rg] = code; }
                }
            }
    }
#pragma unroll
    for (int off = 1; off < 16; off <<= 1)
#pragma unroll
        for (int mt = 0; mt < 2; ++mt)
#pragma unroll
            for (int rg = 0; rg < 4; ++rg) {
                float os = __shfl_xor(best[mt][rg], off, 64);
                int   oi = __shfl_xor(bidx[mt][rg], off, 64);
                if (os < best[mt][rg] || (os == best[mt][rg] && oi < bidx[mt][rg])) {
                    best[mt][rg] = os; bidx[mt][rg] = oi;
                }
            }
    float* epmin = reinterpret_cast<float*>(lds);
    int*   epidx = reinterpret_cast<int*>(reinterpret_cast<char*>(lds) + 512);
    int*   fbidx = reinterpret_cast<int*>(reinterpret_cast<char*>(lds) + 1024);
    float* lred  = reinterpret_cast<float*>(reinterpret_cast<char*>(lds) + 1280);
    __syncthreads();
    if (m15 == 0) {
        int g = wid & 1;
#pragma unroll
        for (int mt = 0; mt < 2; ++mt)
#pragma unroll
            for (int rg = 0; rg < 4; ++rg) {
                int row = wrow + (mt << 4) + (q << 2) + rg;
                epmin[g * 64 + row] = best[mt][rg];
                epidx[g * 64 + row] = bidx[mt][rg];
            }
    }
    __syncthreads();
    if (t < 64) {
        float s0 = epmin[t], s1 = epmin[64 + t];
        int   i0 = epidx[t], i1 = epidx[64 + t];
        int   fi = (s1 < s0 || (s1 == s0 && i1 < i0)) ? i1 : i0;
        fbidx[t] = fi;
        out_idx[rowBase + t] = (float)fi;
    }
    __syncthreads();
    const float4* z4 = reinterpret_cast<const float4*>(z);
    float lsum = 0.0f;
#pragma unroll
    for (int i = 0; i < 8; ++i) {
        int g = i * 256 + t;
        int r = g >> 5, f4 = g & 31;
        int code = fbidx[r];
        float4 wv = *reinterpret_cast<const float4*>(w + (size_t)code * HH + (f4 << 2));
        float4 zv = z4[(size_t)(rowBase + r) * 32 + f4];
        float dx = wv.x - zv.x, dy = wv.y - zv.y, dz = wv.z - zv.z, dw = wv.w - zv.w;
        lsum = fmaf(dx, dx, lsum); lsum = fmaf(dy, dy, lsum);
        lsum = fmaf(dz, dz, lsum); lsum = fmaf(dw, dw, lsum);
        *reinterpret_cast<float4*>(out_zq + (size_t)(rowBase + r) * HH + (f4 << 2)) = wv;
    }
#pragma unroll
    for (int off = 1; off < 64; off <<= 1) lsum += __shfl_xor(lsum, off, 64);
    if (lane == 0) lred[wid] = lsum;
    __syncthreads();
    if (t == 0)
        atomicAdd(out_loss, (lred[0] + lred[1] + lred[2] + lred[3]) * (1.25f / 4194304.0f));
}

extern "C" void kernel_launch(void* const* d_in, const int* in_sizes, int n_in,
                              void* d_out, int out_size, void* d_ws, size_t ws_size,
                              hipStream_t stream) {
    (void)in_sizes; (void)n_in; (void)out_size;
    const float* z = (const float*)d_in[0];
    const float* w = (const float*)d_in[1];
    float* out      = (float*)d_out;
    float* out_zq   = out;
    float* out_idx  = out + (size_t)NROWS * HH;
    float* out_loss = out_idx + NROWS;

    // ws offsets (bytes)
    char* wsb = (char*)d_ws;
    float* wsqR    = (float*)(wsb + 0);
    float* wlPart  = (float*)(wsb + 16384);
    float* whPart  = (float*)(wsb + 17408);
    unsigned int* nFlag = (unsigned int*)(wsb + 18432);
    ushort* whiA   = (ushort*)(wsb + 18688);
    int* idxInt    = (int*)(wsb + 1067264);
    int* slotOf    = (int*)(wsb + 1198336);
    int* clist     = (int*)(wsb + 1329408);
    float* pminR   = (float*)(wsb + 1394944);
    int* pidxR     = (int*)(wsb + 1657088);
    const size_t WS_NEED = 1919232;

    // d_out zq-region scratch (dead before vq_final overwrites it)
    float* pm1 = out_zq;
    int*   pi1 = (int*)(out_zq + 65536);
    float* pm2 = out_zq + 131072;
    float* znA = out_zq + 196608;
    float* zlA = out_zq + 229376;

    if (ws_size >= WS_NEED) {
        vq_prep<<<256, 256, 0, stream>>>(w, wsqR, whiA, wlPart, whPart);
        vq_p1<<<1024, 512, 0, stream>>>(z, whiA, wsqR, pm1, pi1, pm2, znA, zlA, nFlag);
        vq_flag<<<128, 256, 0, stream>>>(pm1, pi1, pm2, znA, zlA, wlPart, whPart,
                                         idxInt, slotOf, clist, nFlag, out_loss);
        vq_rescan<<<1024, 256, 0, stream>>>(z, w, whiA, wsqR, clist, nFlag, pminR, pidxR);
        vq_final<<<512, 256, 0, stream>>>(z, w, idxInt, slotOf, pminR, pidxR,
                                          out_zq, out_idx, out_loss);
    } else {
        float* wsq = (float*)d_ws;
        vq_prep_fb<<<KCODES / 256, 256, 0, stream>>>(w, wsq, out_loss);
        vq_main_fb<<<NROWS / 64, 256, 0, stream>>>(z, w, wsq, out_zq, out_idx, out_loss);
    }
}

// Round 7
// 146.600 us; speedup vs baseline: 1.3375x; 1.2885x over previous
//
#include <hip/hip_runtime.h>
#include <float.h>
#include <stdint.h>

#define HH 128
#define NROWS 32768
#define KCODES 4096
#define CAPR 40

typedef _Float16 half8 __attribute__((ext_vector_type(8)));
typedef _Float16 half4_t __attribute__((ext_vector_type(4)));
typedef float floatx4 __attribute__((ext_vector_type(4)));
typedef float floatx16 __attribute__((ext_vector_type(16)));

// order-preserving float<->uint key (handles negatives) for LDS atomicMin
__device__ __forceinline__ unsigned fkey(float f) {
    unsigned b = __float_as_uint(f);
    return b ^ ((unsigned)((int)b >> 31) | 0x80000000u);
}
__device__ __forceinline__ float funkey(unsigned k) {
    unsigned b = (k & 0x80000000u) ? (k ^ 0x80000000u) : ~k;
    return __uint_as_float(b);
}

// ---------------------------------------------------------------------------
// ws layout (bytes): 0 wq2R float[4096] (0.5*||w||^2 in C-layout) | 16384
// whPart float[256] | 17408 whiA ushort[524288] (1 MB, A-frag order).
// whiA: chunk (cb = code>>5, s = h/16) = 512 ushorts; entry lane = kh*32 +
// (code&31) holds w_hi[code][s*16 + kh*8 .. +8]  (validated R6 p1 path).
// wq2R[cb*32 + kh*16 + r] = 0.5*||w||^2 of code cb*32+(r&3)+8*(r>>2)+4*kh,
// i.e. exactly the MFMA C-operand register order (m74/m101 C/D layout).
// ---------------------------------------------------------------------------

__global__ __launch_bounds__(256) void vq_prep(const float* __restrict__ w,
        float* __restrict__ wq2R, ushort* __restrict__ whiA,
        float* __restrict__ whPart, float* __restrict__ loss_slot) {
    __shared__ float sWH[16];
    const int t = threadIdx.x;
    const int tid = blockIdx.x * 256 + t;
    if (tid == 0) loss_slot[0] = 0.0f;   // d_out poisoned 0xAA each launch
    const int c = tid >> 4, hg = tid & 15, s = hg >> 1, khh = hg & 1;

    const float4* src = reinterpret_cast<const float4*>(w + (size_t)c * HH + (hg << 3));
    float4 a = src[0], b = src[1];
    _Float16 h0=(_Float16)a.x, h1=(_Float16)a.y, h2=(_Float16)a.z, h3=(_Float16)a.w;
    _Float16 h4=(_Float16)b.x, h5=(_Float16)b.y, h6=(_Float16)b.z, h7=(_Float16)b.w;
    half8 hi = {h0, h1, h2, h3, h4, h5, h6, h7};
    *reinterpret_cast<half8*>(&whiA[((size_t)(c >> 5) * 8 + s) * 512 +
                                    (((khh << 5) | (c & 31)) << 3)]) = hi;

    float ssq = 0.f;
    ssq = fmaf(a.x, a.x, ssq); ssq = fmaf(a.y, a.y, ssq);
    ssq = fmaf(a.z, a.z, ssq); ssq = fmaf(a.w, a.w, ssq);
    ssq = fmaf(b.x, b.x, ssq); ssq = fmaf(b.y, b.y, ssq);
    ssq = fmaf(b.z, b.z, ssq); ssq = fmaf(b.w, b.w, ssq);
    ssq += __shfl_xor(ssq, 1, 64);
    ssq += __shfl_xor(ssq, 2, 64);
    ssq += __shfl_xor(ssq, 4, 64);
    ssq += __shfl_xor(ssq, 8, 64);
    if (hg == 0) {
        int co = c & 31;
        wq2R[((c >> 5) << 5) + (((co >> 2) & 1) << 4) + ((co & 3) | ((co >> 3) << 2))]
            = 0.5f * ssq;
        sWH[t >> 4] = ssq;
    }
    __syncthreads();
    if (t == 0) {
        float mh = 0.f;
#pragma unroll
        for (int i = 0; i < 16; ++i) mh = fmaxf(mh, sWH[i]);
        whPart[blockIdx.x] = mh;
    }
}

// ---------------------------------------------------------------------------
// Fused: hi-fp16 candidate-collecting scan (no LDS tiles, no k-loop barriers)
// + exact fp32 eval of candidates + zq/loss epilogue. Block = 32 rows,
// 4 waves x 1024-code quarters; codes-as-M (A), z rows as B (lane-resident).
// ---------------------------------------------------------------------------
__global__ __launch_bounds__(256, 2) void vq_fused(
        const float* __restrict__ z, const float* __restrict__ w,
        const float* __restrict__ wq2R, const ushort* __restrict__ whiA,
        const float* __restrict__ whPart,
        float* __restrict__ out_zq, float* __restrict__ out_idx,
        float* __restrict__ out_loss) {
    __shared__ unsigned smin[32];
    __shared__ int rowcnt[32];
    __shared__ int rowovf[32];
    __shared__ int rowlist[32 * CAPR];
    __shared__ float swh[4];
    __shared__ int fb[32];
    __shared__ float lred[4];

    const int t = threadIdx.x;
    const int lane = t & 63, wid = t >> 6;
    const int n = lane & 31, kh = lane >> 5;
    const int rowBase = blockIdx.x * 32;

    // codebook max ||w||^2 partial reduce (256 partials from prep)
    float wp = whPart[t];
#pragma unroll
    for (int off = 1; off < 64; off <<= 1) wp = fmaxf(wp, __shfl_xor(wp, off, 64));
    if (lane == 0) swh[wid] = wp;
    if (t < 32) { smin[t] = 0xFFFFFFFFu; rowcnt[t] = 0; rowovf[t] = 0; }

    // ---- stage z: NEGATED hi fp16 B-frags (row = n, k-half = kh) + norms ----
    half8 zb[8];
    float zn2 = 0.f, zl2 = 0.f;
    {
        const float* zr = z + (size_t)(rowBase + n) * HH + (kh << 3);
#pragma unroll
        for (int s = 0; s < 8; ++s) {
            float4 a = *reinterpret_cast<const float4*>(zr + (s << 4));
            float4 b = *reinterpret_cast<const float4*>(zr + (s << 4) + 4);
            _Float16 h0=(_Float16)a.x, h1=(_Float16)a.y, h2=(_Float16)a.z, h3=(_Float16)a.w;
            _Float16 h4=(_Float16)b.x, h5=(_Float16)b.y, h6=(_Float16)b.z, h7=(_Float16)b.w;
            zb[s] = (half8){-h0, -h1, -h2, -h3, -h4, -h5, -h6, -h7};
            zn2 = fmaf(a.x,a.x,zn2); zn2 = fmaf(a.y,a.y,zn2);
            zn2 = fmaf(a.z,a.z,zn2); zn2 = fmaf(a.w,a.w,zn2);
            zn2 = fmaf(b.x,b.x,zn2); zn2 = fmaf(b.y,b.y,zn2);
            zn2 = fmaf(b.z,b.z,zn2); zn2 = fmaf(b.w,b.w,zn2);
            float l0=a.x-(float)h0, l1=a.y-(float)h1, l2=a.z-(float)h2, l3=a.w-(float)h3;
            float l4=b.x-(float)h4, l5=b.y-(float)h5, l6=b.z-(float)h6, l7=b.w-(float)h7;
            zl2 = fmaf(l0,l0,zl2); zl2 = fmaf(l1,l1,zl2);
            zl2 = fmaf(l2,l2,zl2); zl2 = fmaf(l3,l3,zl2);
            zl2 = fmaf(l4,l4,zl2); zl2 = fmaf(l5,l5,zl2);
            zl2 = fmaf(l6,l6,zl2); zl2 = fmaf(l7,l7,zl2);
        }
        zn2 += __shfl_xor(zn2, 32, 64);
        zl2 += __shfl_xor(zl2, 32, 64);
    }
    __syncthreads();   // smin/cnt init + swh visible

    // rigorous window: |d/2_true - sc| <= E; accept if sc < runmin + thrw,
    // thrw > 2E  =>  true argmin always collected; non-collected strictly worse
    float WH = sqrtf(fmaxf(fmaxf(swh[0], swh[1]), fmaxf(swh[2], swh[3])));
    float thrw;
    {
        float znr = sqrtf(zn2), zlr = sqrtf(zl2);
        float E = zlr * WH * 1.01f + (znr + zlr) * (WH * 4.8828125e-4f + 1e-6f) + 4e-3f;
        thrw = 2.0f * E * 1.05f + 0.01f;
    }

    const half8* A8 = reinterpret_cast<const half8*>(whiA);
    const int cb0 = wid << 5;
    float m1 = FLT_MAX;

    half8 afA[8], afB[8];
    floatx16 wqA, wqB;
    {
        const half8* ap = A8 + ((size_t)cb0 << 3) * 64 + lane;
#pragma unroll
        for (int p = 0; p < 8; ++p) afA[p] = ap[p * 64];
        wqA = *reinterpret_cast<const floatx16*>(wq2R + (cb0 << 5) + (kh << 4));
    }

    auto body = [&](int it, half8 (&cur)[8], floatx16& wqcur,
                    half8 (&nxt)[8], floatx16& wqnxt) {
        const int cb = cb0 + ((it < 32) ? it : 0);
        if (it < 32) {
            const int cbn = cb0 + ((it + 1) & 31);
            const half8* ap = A8 + ((size_t)cbn << 3) * 64 + lane;
#pragma unroll
            for (int p = 0; p < 8; ++p) nxt[p] = ap[p * 64];
            wqnxt = *reinterpret_cast<const floatx16*>(wq2R + (cbn << 5) + (kh << 4));
        }
        // acc = wq2 + (-zh)·wh = d/2 estimate; C-init from loaded wq2 (no movs)
        floatx16 acc = __builtin_amdgcn_mfma_f32_32x32x16_f16(cur[0], zb[0], wqcur, 0, 0, 0);
#pragma unroll
        for (int s = 1; s < 8; ++s)
            acc = __builtin_amdgcn_mfma_f32_32x32x16_f16(cur[s], zb[s], acc, 0, 0, 0);

        float t00=fminf(acc[0],acc[1]),   t01=fminf(acc[2],acc[3]);
        float t02=fminf(acc[4],acc[5]),   t03=fminf(acc[6],acc[7]);
        float t04=fminf(acc[8],acc[9]),   t05=fminf(acc[10],acc[11]);
        float t06=fminf(acc[12],acc[13]), t07=fminf(acc[14],acc[15]);
        float tmin = fminf(fminf(fminf(t00,t01), fminf(t02,t03)),
                           fminf(fminf(t04,t05), fminf(t06,t07)));
        m1 = fminf(m1, tmin);
        atomicMin(&smin[n], fkey(m1));
        if (it > 0) {   // tile 0 collected on the it==32 re-pass (warm bound)
            float sh = funkey(((volatile unsigned*)smin)[n]);
            float bound = fminf(sh, m1) + thrw;
            if (tmin < bound) {
#pragma unroll
                for (int r = 0; r < 16; ++r) {
                    if (acc[r] < bound) {
                        int code = (cb << 5) + (r & 3) + ((r >> 2) << 3) + (kh << 2);
                        int ix = atomicAdd(&rowcnt[n], 1);
                        if (ix < CAPR) rowlist[n * CAPR + ix] = code;
                        else rowovf[n] = 1;
                    }
                }
            }
        }
    };

#pragma unroll 1
    for (int itp = 0; itp < 16; ++itp) {
        body(2 * itp,     afA, wqA, afB, wqB);
        body(2 * itp + 1, afB, wqB, afA, wqA);
    }
    body(32, afA, wqA, afB, wqB);   // re-pass tile 0
    __syncthreads();

    // ---- exact fp32 eval of candidates (8 threads per row) ----
    {
        const int erow = t >> 3, eq = t & 7;
        int cnt = rowcnt[erow];
        bool ovf = (rowovf[erow] != 0) || (cnt > CAPR) || (cnt == 0);
        if (cnt > CAPR) cnt = CAPR;
        if (ovf) {
            if (eq == 0) rowovf[erow] = 1;
        } else {
            const float* zs = z + (size_t)(rowBase + erow) * HH + (eq << 4);
            float4 za = *reinterpret_cast<const float4*>(zs);
            float4 zb4 = *reinterpret_cast<const float4*>(zs + 4);
            float4 zc = *reinterpret_cast<const float4*>(zs + 8);
            float4 zd = *reinterpret_cast<const float4*>(zs + 12);
            float bd = FLT_MAX; int bc = 0x7fffffff;
            for (int j = 0; j < cnt; ++j) {
                int c = rowlist[erow * CAPR + j];
                const float* wr = w + (size_t)c * HH + (eq << 4);
                float4 wa = *reinterpret_cast<const float4*>(wr);
                float4 wb = *reinterpret_cast<const float4*>(wr + 4);
                float4 wc = *reinterpret_cast<const float4*>(wr + 8);
                float4 wd = *reinterpret_cast<const float4*>(wr + 12);
                float dot = 0.f;
                dot = fmaf(za.x,wa.x,dot); dot = fmaf(za.y,wa.y,dot);
                dot = fmaf(za.z,wa.z,dot); dot = fmaf(za.w,wa.w,dot);
                dot = fmaf(zb4.x,wb.x,dot); dot = fmaf(zb4.y,wb.y,dot);
                dot = fmaf(zb4.z,wb.z,dot); dot = fmaf(zb4.w,wb.w,dot);
                dot = fmaf(zc.x,wc.x,dot); dot = fmaf(zc.y,wc.y,dot);
                dot = fmaf(zc.z,wc.z,dot); dot = fmaf(zc.w,wc.w,dot);
                dot = fmaf(zd.x,wd.x,dot); dot = fmaf(zd.y,wd.y,dot);
                dot = fmaf(zd.z,wd.z,dot); dot = fmaf(zd.w,wd.w,dot);
                dot += __shfl_xor(dot, 1, 64);
                dot += __shfl_xor(dot, 2, 64);
                dot += __shfl_xor(dot, 4, 64);
                int co = c & 31;
                float wq2v = wq2R[((c >> 5) << 5) + (((co >> 2) & 1) << 4)
                                  + ((co & 3) | ((co >> 3) << 2))];
                float d2 = wq2v - dot;
                if (d2 < bd || (d2 == bd && c < bc)) { bd = d2; bc = c; }
            }
            if (eq == 0) { fb[erow] = bc; out_idx[rowBase + erow] = (float)bc; }
        }
    }
    __syncthreads();

    // ---- rigorous fallback: full exact scan for overflow rows (≈never) ----
    if (wid == 0) {
        for (int rr = 0; rr < 32; ++rr) {
            if (rowovf[rr] == 0) continue;
            const float* zrow = z + (size_t)(rowBase + rr) * HH;
            float bd = FLT_MAX; int bc = 0x7fffffff;
            for (int kq = 0; kq < 64; ++kq) {
                int c = (kq << 6) + lane;
                const float* wr = w + (size_t)c * HH;
                float dot = 0.f;
                for (int h4 = 0; h4 < 32; ++h4) {
                    float4 wv = *reinterpret_cast<const float4*>(wr + (h4 << 2));
                    float4 zv = *reinterpret_cast<const float4*>(zrow + (h4 << 2));
                    dot = fmaf(zv.x,wv.x,dot); dot = fmaf(zv.y,wv.y,dot);
                    dot = fmaf(zv.z,wv.z,dot); dot = fmaf(zv.w,wv.w,dot);
                }
                int co = c & 31;
                float wq2v = wq2R[((c >> 5) << 5) + (((co >> 2) & 1) << 4)
                                  + ((co & 3) | ((co >> 3) << 2))];
                float d2 = wq2v - dot;
                if (d2 < bd || (d2 == bd && c < bc)) { bd = d2; bc = c; }
            }
#pragma unroll
            for (int off = 1; off < 64; off <<= 1) {
                float od = __shfl_xor(bd, off, 64);
                int oc = __shfl_xor(bc, off, 64);
                if (od < bd || (od == bd && oc < bc)) { bd = od; bc = oc; }
            }
            if (lane == 0) { fb[rr] = bc; out_idx[rowBase + rr] = (float)bc; }
        }
    }
    __syncthreads();

    // ---- zq gather + loss (proven epilogue) ----
    const float4* z4 = reinterpret_cast<const float4*>(z);
    float lsum = 0.f;
#pragma unroll
    for (int i = 0; i < 4; ++i) {
        int g = i * 256 + t;
        int r = g >> 5, f4 = g & 31;
        int code = fb[r];
        float4 wv = *reinterpret_cast<const float4*>(w + (size_t)code * HH + (f4 << 2));
        float4 zv = z4[(size_t)(rowBase + r) * 32 + f4];
        float dx = wv.x - zv.x, dy = wv.y - zv.y, dz = wv.z - zv.z, dw = wv.w - zv.w;
        lsum = fmaf(dx, dx, lsum); lsum = fmaf(dy, dy, lsum);
        lsum = fmaf(dz, dz, lsum); lsum = fmaf(dw, dw, lsum);
        *reinterpret_cast<float4*>(out_zq + (size_t)(rowBase + r) * HH + (f4 << 2)) = wv;
    }
#pragma unroll
    for (int off = 1; off < 64; off <<= 1) lsum += __shfl_xor(lsum, off, 64);
    if (lane == 0) lred[wid] = lsum;
    __syncthreads();
    if (t == 0) {
        float total = lred[0] + lred[1] + lred[2] + lred[3];
        atomicAdd(out_loss, total * (1.25f / 4194304.0f));  // (0.25+1)*mean, N*H
    }
}

// ---------------- fallback path (Round-2 kernels, proven) -------------------
__device__ __forceinline__ int plane_off_fb(int r, int hu) {
    return ((hu << 6) | (r ^ (hu & 7))) << 3;
}

__global__ __launch_bounds__(256) void vq_prep_fb(const float* __restrict__ w,
                                                  float* __restrict__ wsq,
                                                  float* __restrict__ loss_slot) {
    int c = blockIdx.x * 256 + threadIdx.x;
    if (c == 0) loss_slot[0] = 0.0f;
    if (c < KCODES) {
        const float4* row = reinterpret_cast<const float4*>(w + (size_t)c * HH);
        float s = 0.0f;
#pragma unroll
        for (int i = 0; i < HH / 4; ++i) {
            float4 v = row[i];
            s = fmaf(v.x, v.x, s); s = fmaf(v.y, v.y, s);
            s = fmaf(v.z, v.z, s); s = fmaf(v.w, v.w, s);
        }
        wsq[c] = s;
    }
}

__device__ __forceinline__ void stage_tile_fb(const float4* __restrict__ src4,
                                              ushort* lds, int hi_base, int lo_base,
                                              int t) {
#pragma unroll
    for (int p = 0; p < 8; ++p) {
        int g = p * 256 + t;
        int r = g >> 5, f4 = g & 31;
        float4 v = src4[g];
        _Float16 h0 = (_Float16)v.x, h1 = (_Float16)v.y,
                 h2 = (_Float16)v.z, h3 = (_Float16)v.w;
        half4_t hv = {h0, h1, h2, h3};
        half4_t lv = {(_Float16)(v.x - (float)h0), (_Float16)(v.y - (float)h1),
                      (_Float16)(v.z - (float)h2), (_Float16)(v.w - (float)h3)};
        int off = plane_off_fb(r, f4 >> 1) + ((f4 & 1) << 2);
        *reinterpret_cast<half4_t*>(&lds[hi_base + off]) = hv;
        *reinterpret_cast<half4_t*>(&lds[lo_base + off]) = lv;
    }
}

__global__ __launch_bounds__(256, 2) void vq_main_fb(const float* __restrict__ z,
                                                     const float* __restrict__ w,
                                                     const float* __restrict__ wsq,
                                                     float* __restrict__ out_zq,
                                                     float* __restrict__ out_idx,
                                                     float* __restrict__ out_loss) {
    __shared__ __align__(16) ushort lds[32768];
    const int t = threadIdx.x, lane = t & 63, wid = t >> 6;
    const int q = lane >> 4, m15 = lane & 15;
    const int wrow = (wid >> 1) << 5, wcol = (wid & 1) << 5;
    const int rowBase = blockIdx.x * 64;

    stage_tile_fb(reinterpret_cast<const float4*>(z + (size_t)rowBase * HH), lds, 0, 8192, t);

    float best[2][4]; int bidx[2][4];
#pragma unroll
    for (int mt = 0; mt < 2; ++mt)
#pragma unroll
        for (int rg = 0; rg < 4; ++rg) { best[mt][rg] = FLT_MAX; bidx[mt][rg] = 0; }

    const int ar0 = wrow + m15, bn0 = wcol + m15;

    for (int k0 = 0; k0 < KCODES; k0 += 64) {
        __syncthreads();
        stage_tile_fb(reinterpret_cast<const float4*>(w + (size_t)k0 * HH), lds, 16384, 24576, t);
        __syncthreads();
        floatx4 acc[2][2];
#pragma unroll
        for (int mt = 0; mt < 2; ++mt)
#pragma unroll
            for (int nt = 0; nt < 2; ++nt) acc[mt][nt] = (floatx4){0.f, 0.f, 0.f, 0.f};
#pragma unroll
        for (int c = 0; c < 4; ++c) {
            const int hu = (c << 2) + q;
            half8 zh0 = *reinterpret_cast<half8*>(&lds[plane_off_fb(ar0, hu)]);
            half8 zh1 = *reinterpret_cast<half8*>(&lds[plane_off_fb(ar0 + 16, hu)]);
            half8 zl0 = *reinterpret_cast<half8*>(&lds[8192 + plane_off_fb(ar0, hu)]);
            half8 zl1 = *reinterpret_cast<half8*>(&lds[8192 + plane_off_fb(ar0 + 16, hu)]);
            half8 wh0 = *reinterpret_cast<half8*>(&lds[16384 + plane_off_fb(bn0, hu)]);
            half8 wh1 = *reinterpret_cast<half8*>(&lds[16384 + plane_off_fb(bn0 + 16, hu)]);
            half8 wl0 = *reinterpret_cast<half8*>(&lds[24576 + plane_off_fb(bn0, hu)]);
            half8 wl1 = *reinterpret_cast<half8*>(&lds[24576 + plane_off_fb(bn0 + 16, hu)]);
            acc[0][0] = __builtin_amdgcn_mfma_f32_16x16x32_f16(zh0, wh0, acc[0][0], 0, 0, 0);
            acc[0][1] = __builtin_amdgcn_mfma_f32_16x16x32_f16(zh0, wh1, acc[0][1], 0, 0, 0);
            acc[1][0] = __builtin_amdgcn_mfma_f32_16x16x32_f16(zh1, wh0, acc[1][0], 0, 0, 0);
            acc[1][1] = __builtin_amdgcn_mfma_f32_16x16x32_f16(zh1, wh1, acc[1][1], 0, 0, 0);
            acc[0][0] = __builtin_amdgcn_mfma_f32_16x16x32_f16(zh0, wl0, acc[0][0], 0, 0, 0);
            acc[0][1] = __builtin_amdgcn_mfma_f32_16x16x32_f16(zh0, wl1, acc[0][1], 0, 0, 0);
            acc[1][0] = __builtin_amdgcn_mfma_f32_16x16x32_f16(zh1, wl0, acc[1][0], 0, 0, 0);
            acc[1][1] = __builtin_amdgcn_mfma_f32_16x16x32_f16(zh1, wl1, acc[1][1], 0, 0, 0);
            acc[0][0] = __builtin_amdgcn_mfma_f32_16x16x32_f16(zl0, wh0, acc[0][0], 0, 0, 0);
            acc[0][1] = __builtin_amdgcn_mfma_f32_16x16x32_f16(zl0, wh1, acc[0][1], 0, 0, 0);
            acc[1][0] = __builtin_amdgcn_mfma_f32_16x16x32_f16(zl1, wh0, acc[1][0], 0, 0, 0);
            acc[1][1] = __builtin_amdgcn_mfma_f32_16x16x32_f16(zl1, wh1, acc[1][1], 0, 0, 0);
        }
        float wq0 = wsq[k0 + bn0], wq1 = wsq[k0 + bn0 + 16];
#pragma unroll
        for (int mt = 0; mt < 2; ++mt)
#pragma unroll
            for (int nt = 0; nt < 2; ++nt) {
                int code = k0 + wcol + (nt << 4) + m15;
                float wqv = nt ? wq1 : wq0;
#pragma unroll
                for (int rg = 0; rg < 4; ++rg) {
                    float s = fmaf(-2.0f, acc[mt][nt][rg], wqv);
                    if (s < best[mt][rg]) { best[mt][rg] = s; bidx[mt][rg] = code; }
                }
            }
    }
#pragma unroll
    for (int off = 1; off < 16; off <<= 1)
#pragma unroll
        for (int mt = 0; mt < 2; ++mt)
#pragma unroll
            for (int rg = 0; rg < 4; ++rg) {
                float os = __shfl_xor(best[mt][rg], off, 64);
                int   oi = __shfl_xor(bidx[mt][rg], off, 64);
                if (os < best[mt][rg] || (os == best[mt][rg] && oi < bidx[mt][rg])) {
                    best[mt][rg] = os; bidx[mt][rg] = oi;
                }
            }
    float* epmin = reinterpret_cast<float*>(lds);
    int*   epidx = reinterpret_cast<int*>(reinterpret_cast<char*>(lds) + 512);
    int*   fbidx = reinterpret_cast<int*>(reinterpret_cast<char*>(lds) + 1024);
    float* lredf = reinterpret_cast<float*>(reinterpret_cast<char*>(lds) + 1280);
    __syncthreads();
    if (m15 == 0) {
        int g = wid & 1;
#pragma unroll
        for (int mt = 0; mt < 2; ++mt)
#pragma unroll
            for (int rg = 0; rg < 4; ++rg) {
                int row = wrow + (mt << 4) + (q << 2) + rg;
                epmin[g * 64 + row] = best[mt][rg];
                epidx[g * 64 + row] = bidx[mt][rg];
            }
    }
    __syncthreads();
    if (t < 64) {
        float s0 = epmin[t], s1 = epmin[64 + t];
        int   i0 = epidx[t], i1 = epidx[64 + t];
        int   fi = (s1 < s0 || (s1 == s0 && i1 < i0)) ? i1 : i0;
        fbidx[t] = fi;
        out_idx[rowBase + t] = (float)fi;
    }
    __syncthreads();
    const float4* z4 = reinterpret_cast<const float4*>(z);
    float lsum = 0.0f;
#pragma unroll
    for (int i = 0; i < 8; ++i) {
        int g = i * 256 + t;
        int r = g >> 5, f4 = g & 31;
        int code = fbidx[r];
        float4 wv = *reinterpret_cast<const float4*>(w + (size_t)code * HH + (f4 << 2));
        float4 zv = z4[(size_t)(rowBase + r) * 32 + f4];
        float dx = wv.x - zv.x, dy = wv.y - zv.y, dz = wv.z - zv.z, dw = wv.w - zv.w;
        lsum = fmaf(dx, dx, lsum); lsum = fmaf(dy, dy, lsum);
        lsum = fmaf(dz, dz, lsum); lsum = fmaf(dw, dw, lsum);
        *reinterpret_cast<float4*>(out_zq + (size_t)(rowBase + r) * HH + (f4 << 2)) = wv;
    }
#pragma unroll
    for (int off = 1; off < 64; off <<= 1) lsum += __shfl_xor(lsum, off, 64);
    if (lane == 0) lredf[wid] = lsum;
    __syncthreads();
    if (t == 0)
        atomicAdd(out_loss, (lredf[0] + lredf[1] + lredf[2] + lredf[3]) * (1.25f / 4194304.0f));
}

extern "C" void kernel_launch(void* const* d_in, const int* in_sizes, int n_in,
                              void* d_out, int out_size, void* d_ws, size_t ws_size,
                              hipStream_t stream) {
    (void)in_sizes; (void)n_in; (void)out_size;
    const float* z = (const float*)d_in[0];
    const float* w = (const float*)d_in[1];
    float* out      = (float*)d_out;
    float* out_zq   = out;
    float* out_idx  = out + (size_t)NROWS * HH;
    float* out_loss = out_idx + NROWS;

    char* wsb = (char*)d_ws;
    float*  wq2R   = (float*)(wsb + 0);        // 16 KB
    float*  whPart = (float*)(wsb + 16384);    // 1 KB
    ushort* whiA   = (ushort*)(wsb + 17408);   // 1 MB
    const size_t WS_NEED = 17408 + (size_t)KCODES * HH * 2;

    if (ws_size >= WS_NEED) {
        vq_prep<<<256, 256, 0, stream>>>(w, wq2R, whiA, whPart, out_loss);
        vq_fused<<<NROWS / 32, 256, 0, stream>>>(z, w, wq2R, whiA, whPart,
                                                 out_zq, out_idx, out_loss);
    } else {
        float* wsq = (float*)d_ws;
        vq_prep_fb<<<KCODES / 256, 256, 0, stream>>>(w, wsq, out_loss);
        vq_main_fb<<<NROWS / 64, 256, 0, stream>>>(z, w, wsq, out_zq, out_idx, out_loss);
    }
}